// Round 1
// baseline (291.230 us; speedup 1.0000x reference)
//
#include <hip/hip_runtime.h>

// Problem: B=4, C=256, H=W=64 (N=4096). Fused QKV 1x1conv -> spatial attention
// (softmax over j only => independent softmax per 64-key chunk) -> channel LN.
// f16 MFMA (32x32x16), fp32 accumulation throughout.

#define CDIM 256
#define NPOS 4096
#define BATCH 4
#define EPSV 1e-5f

typedef _Float16 f16;
typedef __attribute__((ext_vector_type(8))) _Float16 f16x8;
typedef __attribute__((ext_vector_type(4))) float f32x4;
typedef __attribute__((ext_vector_type(16))) float f32x16;

// Padded LDS strides (elements). Rows must be 16B-aligned for ds_read_b128
// => stride multiple of 8 f16 / 4 f32. 264*2B=528=33*16 OK; 72*2=144=9*16 OK;
// 68*4=272=17*16 OK. Frag-read bank spacing 4*idx mod 32 => 4-way (1.58x, ok).
#define QK_STRIDE 264
#define V_STRIDE  72
#define S_STRIDE  68
#define P_STRIDE  72

// MFMA 32x32x16 f16 layouts (per cdna4 docs; C/D verified m74/m101, A per m120 analog):
//   A: lane l holds A[m][k], m = l&31, k = (l>>5)*8 + j   (j=0..7)
//   B: lane l holds B[k][n], n = l&31, k = (l>>5)*8 + j
//   C/D: lane l, reg r -> col = l&31, row = (r&3) + 8*(r>>2) + 4*(l>>5)

static __device__ __forceinline__ f16x8 cvt8(const float* __restrict__ p) {
    float4 w0 = *(const float4*)p;
    float4 w1 = *(const float4*)(p + 4);
    f16x8 r;
    r[0] = (f16)w0.x; r[1] = (f16)w0.y; r[2] = (f16)w0.z; r[3] = (f16)w0.w;
    r[4] = (f16)w1.x; r[5] = (f16)w1.y; r[6] = (f16)w1.z; r[7] = (f16)w1.w;
    return r;
}

// ---------------------------------------------------------------------------
// Kernel 1: QKV projection. Grid 256 = (b<<6 | ptile), 256 threads (4 waves).
// Q,K stored f16 [B][N][C]; V stored f16 [B][C][N].
// ---------------------------------------------------------------------------
__global__ __launch_bounds__(256, 1) void qkv_kernel(
    const float* __restrict__ x1, const float* __restrict__ x2,
    const float* __restrict__ qw, const float* __restrict__ qb,
    const float* __restrict__ kw, const float* __restrict__ kb,
    const float* __restrict__ vw, const float* __restrict__ vb,
    f16* __restrict__ Qg, f16* __restrict__ Kg, f16* __restrict__ Vg)
{
    __shared__ f16 xT[64 * QK_STRIDE];   // [p][c] f16, 33.8 KB

    const int t  = threadIdx.x;
    const int b  = blockIdx.x >> 6;
    const int p0 = (blockIdx.x & 63) << 6;

    const int w  = t >> 6;
    const int l  = t & 63;
    const int lm = l & 31;
    const int lh = l >> 5;
    const int pt  = w & 1;          // p-tile (2 x 32 rows)
    const int otg = (w >> 1) * 4;   // this wave's 4 o-tiles

    // Stage x (transpose [c][p] fp32 -> [p][c] f16): coalesced dword reads,
    // paired f16 LDS writes.
    auto stage_x = [&](const float* __restrict__ xs) {
        const int p  = t & 63;
        const int cg = (t >> 6) * 2;
        const float* s = xs + (size_t)b * CDIM * NPOS + p0 + p;
        for (int c = cg; c < CDIM; c += 8) {
            float a0 = s[(size_t)c * NPOS];
            float a1 = s[(size_t)(c + 1) * NPOS];
            f16* d = &xT[p * QK_STRIDE + c];
            d[0] = (f16)a0; d[1] = (f16)a1;
        }
    };

    // GEMM D[p][o] = sum_c xT[p][c] * W[o][c] (+bias), store [B][N][C]
    auto proj_pn = [&](const float* __restrict__ W, const float* __restrict__ Bv,
                       f16* __restrict__ Out) {
        f32x16 acc[4] = {};
        for (int ks = 0; ks < 16; ++ks) {
            f16x8 a = *(const f16x8*)&xT[(pt * 32 + lm) * QK_STRIDE + ks * 16 + lh * 8];
            for (int oi = 0; oi < 4; ++oi) {
                int o = (otg + oi) * 32 + lm;                 // B operand n-index
                f16x8 bf = cvt8(W + (size_t)o * CDIM + ks * 16 + lh * 8);
                acc[oi] = __builtin_amdgcn_mfma_f32_32x32x16_f16(a, bf, acc[oi], 0, 0, 0);
            }
        }
        for (int oi = 0; oi < 4; ++oi) {
            int o = (otg + oi) * 32 + lm;
            float bias = Bv[o];
            f16* dst = Out + (size_t)(b * NPOS + p0 + pt * 32) * CDIM + o;
            for (int r = 0; r < 16; ++r) {
                int row = (r & 3) + 8 * (r >> 2) + 4 * lh;    // p within tile
                dst[(size_t)row * CDIM] = (f16)(acc[oi][r] + bias);
            }
        }
    };

    stage_x(x1);
    __syncthreads();
    proj_pn(qw, qb, Qg);
    __syncthreads();
    stage_x(x2);
    __syncthreads();
    proj_pn(kw, kb, Kg);

    // V: D[o][p] = sum_c vw[o][c] * xT2[p][c] (+bias), store [B][C][N]
    {
        f32x16 acc[4] = {};
        for (int ks = 0; ks < 16; ++ks) {
            f16x8 bx = *(const f16x8*)&xT[(pt * 32 + lm) * QK_STRIDE + ks * 16 + lh * 8];
            for (int oi = 0; oi < 4; ++oi) {
                int o = (otg + oi) * 32 + lm;                 // A operand m-index
                f16x8 af = cvt8(vw + (size_t)o * CDIM + ks * 16 + lh * 8);
                acc[oi] = __builtin_amdgcn_mfma_f32_32x32x16_f16(af, bx, acc[oi], 0, 0, 0);
            }
        }
        for (int oi = 0; oi < 4; ++oi) {
            for (int r = 0; r < 16; ++r) {
                int o = (otg + oi) * 32 + (r & 3) + 8 * (r >> 2) + 4 * lh;  // D row
                float bias = vb[o];
                Vg[(size_t)(b * CDIM + o) * NPOS + p0 + pt * 32 + lm] =
                    (f16)(acc[oi][r] + bias);
            }
        }
    }
}

// ---------------------------------------------------------------------------
// Kernel 2: fused attention + LayerNorm. Grid 256 = (b<<6 | qtile), 256 thr.
// Per block: 64 queries, loop over 64 key-chunks of 64 (each = one complete
// softmax segment -> no online-softmax state). LDS ~132.5 KB (gfx950 160KB).
// ---------------------------------------------------------------------------
__global__ __launch_bounds__(256, 1) void attn_kernel(
    const f16* __restrict__ Qg, const f16* __restrict__ Kg, const f16* __restrict__ Vg,
    const float* __restrict__ ln_w, const float* __restrict__ ln_b,
    float* __restrict__ out)
{
    __shared__ f16   Qs[64 * QK_STRIDE];    // 33792 B  [p][c]
    __shared__ f16   Ks[64 * QK_STRIDE];    // 33792 B  [key][c]
    __shared__ f16   Vs[256 * V_STRIDE];    // 36864 B  [c][key]
    __shared__ float Ss[64 * S_STRIDE];     // 17408 B  [p][key] fp32 scores
    __shared__ f16   Ps[64 * P_STRIDE];     //  9216 B  [p][key] f16 probs
    __shared__ float lnw_s[256], lnb_s[256];
    __shared__ float redS[4 * 64], redQ[4 * 64], mu_s[64], rs_s[64];

    const int t  = threadIdx.x;
    const int b  = blockIdx.x >> 6;
    const int p0 = (blockIdx.x & 63) << 6;
    const int w  = t >> 6;
    const int l  = t & 63;
    const int lm = l & 31;
    const int lh = l >> 5;

    // Stage Q tile [64][256] f16 (rows are contiguous 512B in [B,N,C]).
    {
        const int pr  = t >> 5;
        const int off = (t & 31) * 8;
        for (int r = 0; r < 8; ++r) {
            int p = r * 8 + pr;
            *(f16x8*)&Qs[p * QK_STRIDE + off] =
                *(const f16x8*)(Qg + (size_t)(b * NPOS + p0 + p) * CDIM + off);
        }
        lnw_s[t] = ln_w[t];
        lnb_s[t] = ln_b[t];
    }

    const int spt = w & 1;    // S-phase: wave owns tile (p-tile spt, key-tile skt)
    const int skt = w >> 1;
    f32x16 facc[4] = {};      // persistent F acc: [i=c-tile(2)][j=p-tile(2)]
    __syncthreads();

    for (int ch = 0; ch < 64; ++ch) {
        const int i0 = ch * 64;

        // ---- stage K [64key][256c] and V [256c][64key] ----
        {
            const int kr = t >> 5, koff = (t & 31) * 8;
            for (int r = 0; r < 8; ++r) {
                int k = r * 8 + kr;
                *(f16x8*)&Ks[k * QK_STRIDE + koff] =
                    *(const f16x8*)(Kg + (size_t)(b * NPOS + i0 + k) * CDIM + koff);
            }
            const int vr = t >> 3, voff = (t & 7) * 8;
            for (int r = 0; r < 8; ++r) {
                int c = r * 32 + vr;
                *(f16x8*)&Vs[c * V_STRIDE + voff] =
                    *(const f16x8*)(Vg + (size_t)(b * CDIM + c) * NPOS + i0 + voff);
            }
        }
        __syncthreads();

        // ---- S = Q K^T : D[p][key], contraction over c (16 ksteps) ----
        f32x16 sacc = {};
        for (int ks = 0; ks < 16; ++ks) {
            f16x8 a  = *(const f16x8*)&Qs[(spt * 32 + lm) * QK_STRIDE + ks * 16 + lh * 8];
            f16x8 bb = *(const f16x8*)&Ks[(skt * 32 + lm) * QK_STRIDE + ks * 16 + lh * 8];
            sacc = __builtin_amdgcn_mfma_f32_32x32x16_f16(a, bb, sacc, 0, 0, 0);
        }
        for (int r = 0; r < 16; ++r) {
            int row = (r & 3) + 8 * (r >> 2) + 4 * lh;
            Ss[(spt * 32 + row) * S_STRIDE + skt * 32 + lm] = sacc[r];
        }
        __syncthreads();

        // ---- softmax per row (64 keys): 4 threads/row x 16 elems ----
        {
            const int r  = t >> 2;
            const int sg = (t & 3) * 16;
            const float* srow = &Ss[r * S_STRIDE + sg];
            float v[16];
            f32x4 a0 = *(const f32x4*)(srow);
            f32x4 a1 = *(const f32x4*)(srow + 4);
            f32x4 a2 = *(const f32x4*)(srow + 8);
            f32x4 a3 = *(const f32x4*)(srow + 12);
            v[0]=a0[0]; v[1]=a0[1]; v[2]=a0[2]; v[3]=a0[3];
            v[4]=a1[0]; v[5]=a1[1]; v[6]=a1[2]; v[7]=a1[3];
            v[8]=a2[0]; v[9]=a2[1]; v[10]=a2[2]; v[11]=a2[3];
            v[12]=a3[0]; v[13]=a3[1]; v[14]=a3[2]; v[15]=a3[3];
            float m = v[0];
            #pragma unroll
            for (int i = 1; i < 16; ++i) m = fmaxf(m, v[i]);
            m = fmaxf(m, __shfl_xor(m, 1));
            m = fmaxf(m, __shfl_xor(m, 2));
            float s = 0.f;
            #pragma unroll
            for (int i = 0; i < 16; ++i) { float e = __expf(v[i] - m); v[i] = e; s += e; }
            s += __shfl_xor(s, 1);
            s += __shfl_xor(s, 2);
            float inv = __builtin_amdgcn_rcpf(s);
            f16x8 h0, h1;
            #pragma unroll
            for (int i = 0; i < 8; ++i) { h0[i] = (f16)(v[i] * inv); h1[i] = (f16)(v[i + 8] * inv); }
            *(f16x8*)&Ps[r * P_STRIDE + sg]     = h0;
            *(f16x8*)&Ps[r * P_STRIDE + sg + 8] = h1;
        }
        __syncthreads();

        // ---- F += V * P^T : D[c][p]; wave = 2 c-tiles x 2 p-tiles ----
        #pragma unroll
        for (int ks = 0; ks < 4; ++ks) {
            f16x8 bp0 = *(const f16x8*)&Ps[lm * P_STRIDE + ks * 16 + lh * 8];
            f16x8 bp1 = *(const f16x8*)&Ps[(32 + lm) * P_STRIDE + ks * 16 + lh * 8];
            f16x8 av0 = *(const f16x8*)&Vs[(w * 64 + lm) * V_STRIDE + ks * 16 + lh * 8];
            f16x8 av1 = *(const f16x8*)&Vs[(w * 64 + 32 + lm) * V_STRIDE + ks * 16 + lh * 8];
            facc[0] = __builtin_amdgcn_mfma_f32_32x32x16_f16(av0, bp0, facc[0], 0, 0, 0);
            facc[1] = __builtin_amdgcn_mfma_f32_32x32x16_f16(av0, bp1, facc[1], 0, 0, 0);
            facc[2] = __builtin_amdgcn_mfma_f32_32x32x16_f16(av1, bp0, facc[2], 0, 0, 0);
            facc[3] = __builtin_amdgcn_mfma_f32_32x32x16_f16(av1, bp1, facc[3], 0, 0, 0);
        }
        __syncthreads();   // protect Ks/Vs/Ss/Ps before next chunk's staging
    }

    // ---- fused LayerNorm over c per position p ----
    float ps0 = 0.f, ps1 = 0.f, pq0 = 0.f, pq1 = 0.f;
    #pragma unroll
    for (int ii = 0; ii < 2; ++ii) {
        #pragma unroll
        for (int r = 0; r < 16; ++r) {
            float a = facc[ii * 2 + 0][r];
            float c = facc[ii * 2 + 1][r];
            ps0 += a; pq0 += a * a;
            ps1 += c; pq1 += c * c;
        }
    }
    ps0 += __shfl_xor(ps0, 32); pq0 += __shfl_xor(pq0, 32);
    ps1 += __shfl_xor(ps1, 32); pq1 += __shfl_xor(pq1, 32);
    if (lh == 0) {
        redS[w * 64 + lm] = ps0;        redQ[w * 64 + lm] = pq0;
        redS[w * 64 + 32 + lm] = ps1;   redQ[w * 64 + 32 + lm] = pq1;
    }
    __syncthreads();
    if (t < 64) {
        float s = redS[t] + redS[64 + t] + redS[128 + t] + redS[192 + t];
        float q = redQ[t] + redQ[64 + t] + redQ[128 + t] + redQ[192 + t];
        float mean = s * (1.0f / 256.0f);
        float var  = q * (1.0f / 256.0f) - mean * mean;
        mu_s[t] = mean;
        rs_s[t] = rsqrtf(var + EPSV);
    }
    __syncthreads();
    #pragma unroll
    for (int ii = 0; ii < 2; ++ii) {
        #pragma unroll
        for (int jj = 0; jj < 2; ++jj) {
            int p = jj * 32 + lm;
            float mu = mu_s[p], rs = rs_s[p];
            float* dst = out + (size_t)b * CDIM * NPOS + p0 + p;
            #pragma unroll
            for (int r = 0; r < 16; ++r) {
                int c = w * 64 + ii * 32 + (r & 3) + 8 * (r >> 2) + 4 * lh;
                float vL = facc[ii * 2 + jj][r];
                dst[(size_t)c * NPOS] = (vL - mu) * rs * lnw_s[c] + lnb_s[c];
            }
        }
    }
}

// ---------------------------------------------------------------------------
extern "C" void kernel_launch(void* const* d_in, const int* in_sizes, int n_in,
                              void* d_out, int out_size, void* d_ws, size_t ws_size,
                              hipStream_t stream)
{
    const float* x1  = (const float*)d_in[0];
    const float* x2  = (const float*)d_in[1];
    const float* qw  = (const float*)d_in[2];
    const float* qb  = (const float*)d_in[3];
    const float* kw  = (const float*)d_in[4];
    const float* kb  = (const float*)d_in[5];
    const float* vw  = (const float*)d_in[6];
    const float* vb  = (const float*)d_in[7];
    const float* lnw = (const float*)d_in[8];
    const float* lnb = (const float*)d_in[9];

    // Workspace: Q,K f16 [B][N][C]; V f16 [B][C][N]  (3 x 8 MB = 24 MB)
    f16* Qg = (f16*)d_ws;
    f16* Kg = Qg + (size_t)BATCH * NPOS * CDIM;
    f16* Vg = Kg + (size_t)BATCH * NPOS * CDIM;

    qkv_kernel<<<256, 256, 0, stream>>>(x1, x2, qw, qb, kw, kb, vw, vb, Qg, Kg, Vg);
    attn_kernel<<<256, 256, 0, stream>>>(Qg, Kg, Vg, lnw, lnb, (float*)d_out);
}

// Round 2
// 263.934 us; speedup vs baseline: 1.1034x; 1.1034x over previous
//
#include <hip/hip_runtime.h>

// Problem: B=4, C=256, H=W=64 (N=4096). Fused QKV 1x1conv -> spatial attention
// (softmax over j only => independent softmax per 64-key chunk) -> channel LN.
// f16 MFMA (32x32x16), fp32 accumulation throughout.
//
// R2: (1) qkv stages weights into LDS as f16 (was: per-MFMA scattered global
//     loads -> 122us latency-bound). (2) attn: K/V loads pipelined one chunk
//     ahead into registers, hidden behind PV; barriers 4->3 per chunk.

#define CDIM 256
#define NPOS 4096
#define BATCH 4
#define EPSV 1e-5f

typedef _Float16 f16;
typedef __attribute__((ext_vector_type(8))) _Float16 f16x8;
typedef __attribute__((ext_vector_type(4))) float f32x4;
typedef __attribute__((ext_vector_type(16))) float f32x16;

// Padded LDS strides (elements). Rows 16B-aligned for ds_read_b128.
#define WST       264
#define QK_STRIDE 264
#define V_STRIDE  72
#define S_STRIDE  68
#define P_STRIDE  72

// MFMA 32x32x16 f16 layouts:
//   A: lane l holds A[m][k], m = l&31, k = (l>>5)*8 + j   (j=0..7)
//   B: lane l holds B[k][n], n = l&31, k = (l>>5)*8 + j
//   C/D: lane l, reg r -> col = l&31, row = (r&3) + 8*(r>>2) + 4*(l>>5)

static __device__ __forceinline__ f16x8 cvt8(const float* __restrict__ p) {
    float4 w0 = *(const float4*)p;
    float4 w1 = *(const float4*)(p + 4);
    f16x8 r;
    r[0] = (f16)w0.x; r[1] = (f16)w0.y; r[2] = (f16)w0.z; r[3] = (f16)w0.w;
    r[4] = (f16)w1.x; r[5] = (f16)w1.y; r[6] = (f16)w1.z; r[7] = (f16)w1.w;
    return r;
}

// ---------------------------------------------------------------------------
// Kernel 1: QKV projection. Grid 256 = (b<<6 | ptile), 256 threads (4 waves).
// Weights staged to LDS in 128-row halves (f16); MFMA reads LDS only.
// Q,K stored f16 [B][N][C]; V stored f16 [B][C][N].
// ---------------------------------------------------------------------------
__global__ __launch_bounds__(256, 1) void qkv_kernel(
    const float* __restrict__ x1, const float* __restrict__ x2,
    const float* __restrict__ qw, const float* __restrict__ qb,
    const float* __restrict__ kw, const float* __restrict__ kb,
    const float* __restrict__ vw, const float* __restrict__ vb,
    f16* __restrict__ Qg, f16* __restrict__ Kg, f16* __restrict__ Vg)
{
    __shared__ f16 xT[2][64 * WST];     // [p][c] f16, 2 x 33.8 KB
    __shared__ f16 Wh[128 * WST];       // weight half [o][c] f16, 67.6 KB

    const int t  = threadIdx.x;
    const int b  = blockIdx.x >> 6;
    const int p0 = (blockIdx.x & 63) << 6;

    const int w  = t >> 6;
    const int l  = t & 63;
    const int lm = l & 31;
    const int lh = l >> 5;
    const int pt = w & 1;           // p-tile (2 x 32 rows)
    const int ot = w >> 1;          // o-tile pair {ot, ot+2} within the half

    // Stage x1 -> xT[0], x2 -> xT[1] (transpose [c][p] fp32 -> [p][c] f16).
    {
        const int p  = t & 63;
        const int cg = (t >> 6) * 2;
        const float* s1 = x1 + (size_t)b * CDIM * NPOS + p0 + p;
        const float* s2 = x2 + (size_t)b * CDIM * NPOS + p0 + p;
        for (int c = cg; c < CDIM; c += 8) {
            float a0 = s1[(size_t)c * NPOS];
            float a1 = s1[(size_t)(c + 1) * NPOS];
            float b0 = s2[(size_t)c * NPOS];
            float b1 = s2[(size_t)(c + 1) * NPOS];
            xT[0][p * WST + c]     = (f16)a0;
            xT[0][p * WST + c + 1] = (f16)a1;
            xT[1][p * WST + c]     = (f16)b0;
            xT[1][p * WST + c + 1] = (f16)b1;
        }
    }

    const float* Wp[3] = {qw, kw, vw};
    const float* Bp[3] = {qb, kb, vb};
    f16*         Op[3] = {Qg, Kg, Vg};

    for (int pr = 0; pr < 3; ++pr) {
        const f16* X = xT[pr == 0 ? 0 : 1];
        for (int h = 0; h < 2; ++h) {
            __syncthreads();   // prev compute done reading Wh (also fences xT stage)
            // Stage weight half: 128 rows x 256 cols fp32 -> f16 LDS, coalesced.
            {
                const float* Wsrc = Wp[pr] + (size_t)h * 128 * CDIM;
                for (int i = 0; i < 16; ++i) {
                    int g    = t + i * 256;
                    int row  = g >> 5;
                    int colc = (g & 31) * 8;
                    *(f16x8*)&Wh[row * WST + colc] = cvt8(Wsrc + (size_t)row * CDIM + colc);
                }
            }
            __syncthreads();

            if (pr < 2) {
                // D[p][o] = sum_c x[p][c] W[o][c]; store [B][N][C]
                f32x16 acc0 = {}, acc1 = {};
                for (int ks = 0; ks < 16; ++ks) {
                    f16x8 a  = *(const f16x8*)&X[(pt * 32 + lm) * WST + ks * 16 + lh * 8];
                    f16x8 b0 = *(const f16x8*)&Wh[(ot * 32 + lm) * WST + ks * 16 + lh * 8];
                    f16x8 b1 = *(const f16x8*)&Wh[((ot + 2) * 32 + lm) * WST + ks * 16 + lh * 8];
                    acc0 = __builtin_amdgcn_mfma_f32_32x32x16_f16(a, b0, acc0, 0, 0, 0);
                    acc1 = __builtin_amdgcn_mfma_f32_32x32x16_f16(a, b1, acc1, 0, 0, 0);
                }
                f16* dstb = Op[pr] + (size_t)(b * NPOS + p0 + pt * 32) * CDIM;
                #pragma unroll
                for (int tt = 0; tt < 2; ++tt) {
                    const f32x16& acc = tt ? acc1 : acc0;
                    int o = h * 128 + (ot + tt * 2) * 32 + lm;
                    float bias = Bp[pr][o];
                    #pragma unroll
                    for (int r = 0; r < 16; ++r) {
                        int row = (r & 3) + 8 * (r >> 2) + 4 * lh;
                        dstb[(size_t)row * CDIM + o] = (f16)(acc[r] + bias);
                    }
                }
            } else {
                // V: D[o][p] = sum_c W[o][c] x[p][c]; store [B][C][N]
                f32x16 acc0 = {}, acc1 = {};
                for (int ks = 0; ks < 16; ++ks) {
                    f16x8 bx = *(const f16x8*)&X[(pt * 32 + lm) * WST + ks * 16 + lh * 8];
                    f16x8 a0 = *(const f16x8*)&Wh[(ot * 32 + lm) * WST + ks * 16 + lh * 8];
                    f16x8 a1 = *(const f16x8*)&Wh[((ot + 2) * 32 + lm) * WST + ks * 16 + lh * 8];
                    acc0 = __builtin_amdgcn_mfma_f32_32x32x16_f16(a0, bx, acc0, 0, 0, 0);
                    acc1 = __builtin_amdgcn_mfma_f32_32x32x16_f16(a1, bx, acc1, 0, 0, 0);
                }
                #pragma unroll
                for (int tt = 0; tt < 2; ++tt) {
                    const f32x16& acc = tt ? acc1 : acc0;
                    #pragma unroll
                    for (int r = 0; r < 16; ++r) {
                        int o = h * 128 + (ot + tt * 2) * 32 + (r & 3) + 8 * (r >> 2) + 4 * lh;
                        float bias = Bp[2][o];
                        Vg[(size_t)(b * CDIM + o) * NPOS + p0 + pt * 32 + lm] =
                            (f16)(acc[r] + bias);
                    }
                }
            }
        }
    }
}

// ---------------------------------------------------------------------------
// Kernel 2: fused attention + LayerNorm. Grid 256 = (b<<6 | qtile), 256 thr.
// Per block: 64 queries, loop over 64 key-chunks of 64 (each = one complete
// softmax segment). K/V global loads pipelined one chunk ahead (hidden behind
// PV); 3 barriers per chunk. LDS ~132.5 KB.
// ---------------------------------------------------------------------------
__global__ __launch_bounds__(256, 1) void attn_kernel(
    const f16* __restrict__ Qg, const f16* __restrict__ Kg, const f16* __restrict__ Vg,
    const float* __restrict__ ln_w, const float* __restrict__ ln_b,
    float* __restrict__ out)
{
    __shared__ f16   Qs[64 * QK_STRIDE];    // 33792 B  [p][c]
    __shared__ f16   Ks[64 * QK_STRIDE];    // 33792 B  [key][c]
    __shared__ f16   Vs[256 * V_STRIDE];    // 36864 B  [c][key]
    __shared__ float Ss[64 * S_STRIDE];     // 17408 B  [p][key] fp32 scores
    __shared__ f16   Ps[64 * P_STRIDE];     //  9216 B  [p][key] f16 probs
    __shared__ float lnw_s[256], lnb_s[256];
    __shared__ float redS[4 * 64], redQ[4 * 64], mu_s[64], rs_s[64];

    const int t  = threadIdx.x;
    const int b  = blockIdx.x >> 6;
    const int p0 = (blockIdx.x & 63) << 6;
    const int w  = t >> 6;
    const int l  = t & 63;
    const int lm = l & 31;
    const int lh = l >> 5;

    // Stage Q tile [64][256] f16 (rows contiguous 512B in [B,N,C]).
    {
        const int pr  = t >> 5;
        const int off = (t & 31) * 8;
        for (int r = 0; r < 8; ++r) {
            int p = r * 8 + pr;
            *(f16x8*)&Qs[p * QK_STRIDE + off] =
                *(const f16x8*)(Qg + (size_t)(b * NPOS + p0 + p) * CDIM + off);
        }
        lnw_s[t] = ln_w[t];
        lnb_s[t] = ln_b[t];
    }

    // K/V prefetch registers (one chunk ahead).
    const int kr = t >> 5, koff = (t & 31) * 8;
    const int vr = t >> 3, voff = (t & 7) * 8;
    f16x8 kreg[8], vreg[8];
    auto issue_loads = [&](int ch) {
        const int i0 = ch * 64;
        #pragma unroll
        for (int r = 0; r < 8; ++r)
            kreg[r] = *(const f16x8*)(Kg + (size_t)(b * NPOS + i0 + r * 8 + kr) * CDIM + koff);
        #pragma unroll
        for (int r = 0; r < 8; ++r)
            vreg[r] = *(const f16x8*)(Vg + (size_t)(b * CDIM + r * 32 + vr) * NPOS + i0 + voff);
    };
    issue_loads(0);

    const int spt = w & 1;    // S-phase: wave owns tile (p-tile spt, key-tile skt)
    const int skt = w >> 1;
    f32x16 facc[4] = {};      // persistent F acc: [i=c-tile(2)][j=p-tile(2)]

    for (int ch = 0; ch < 64; ++ch) {
        // ---- commit prefetched K to LDS (Ks unread since prev S-phase) ----
        #pragma unroll
        for (int r = 0; r < 8; ++r)
            *(f16x8*)&Ks[(r * 8 + kr) * QK_STRIDE + koff] = kreg[r];
        __syncthreads();   // A: Qs+Ks ready; prev PV done (Vs/Ps free)

        // ---- commit V to LDS (overlaps with S-phase below) ----
        #pragma unroll
        for (int r = 0; r < 8; ++r)
            *(f16x8*)&Vs[(r * 32 + vr) * V_STRIDE + voff] = vreg[r];

        // ---- S = Q K^T : D[p][key], contraction over c (16 ksteps) ----
        f32x16 sacc = {};
        for (int ks = 0; ks < 16; ++ks) {
            f16x8 a  = *(const f16x8*)&Qs[(spt * 32 + lm) * QK_STRIDE + ks * 16 + lh * 8];
            f16x8 bb = *(const f16x8*)&Ks[(skt * 32 + lm) * QK_STRIDE + ks * 16 + lh * 8];
            sacc = __builtin_amdgcn_mfma_f32_32x32x16_f16(a, bb, sacc, 0, 0, 0);
        }
        #pragma unroll
        for (int r = 0; r < 16; ++r) {
            int row = (r & 3) + 8 * (r >> 2) + 4 * lh;
            Ss[(spt * 32 + row) * S_STRIDE + skt * 32 + lm] = sacc[r];
        }
        __syncthreads();   // B: Ss ready; Vs writes fenced

        // ---- softmax per row (64 keys): 4 threads/row x 16 elems ----
        {
            const int r  = t >> 2;
            const int sg = (t & 3) * 16;
            const float* srow = &Ss[r * S_STRIDE + sg];
            float v[16];
            f32x4 a0 = *(const f32x4*)(srow);
            f32x4 a1 = *(const f32x4*)(srow + 4);
            f32x4 a2 = *(const f32x4*)(srow + 8);
            f32x4 a3 = *(const f32x4*)(srow + 12);
            v[0]=a0[0]; v[1]=a0[1]; v[2]=a0[2]; v[3]=a0[3];
            v[4]=a1[0]; v[5]=a1[1]; v[6]=a1[2]; v[7]=a1[3];
            v[8]=a2[0]; v[9]=a2[1]; v[10]=a2[2]; v[11]=a2[3];
            v[12]=a3[0]; v[13]=a3[1]; v[14]=a3[2]; v[15]=a3[3];
            float m = v[0];
            #pragma unroll
            for (int i = 1; i < 16; ++i) m = fmaxf(m, v[i]);
            m = fmaxf(m, __shfl_xor(m, 1));
            m = fmaxf(m, __shfl_xor(m, 2));
            float s = 0.f;
            #pragma unroll
            for (int i = 0; i < 16; ++i) { float e = __expf(v[i] - m); v[i] = e; s += e; }
            s += __shfl_xor(s, 1);
            s += __shfl_xor(s, 2);
            float inv = __builtin_amdgcn_rcpf(s);
            f16x8 h0, h1;
            #pragma unroll
            for (int i = 0; i < 8; ++i) { h0[i] = (f16)(v[i] * inv); h1[i] = (f16)(v[i + 8] * inv); }
            *(f16x8*)&Ps[r * P_STRIDE + sg]     = h0;
            *(f16x8*)&Ps[r * P_STRIDE + sg + 8] = h1;
        }
        __syncthreads();   // C: Ps ready

        // ---- prefetch next chunk's K/V (latency hidden behind PV) ----
        if (ch < 63) issue_loads(ch + 1);

        // ---- F += V * P^T : D[c][p]; wave = 2 c-tiles x 2 p-tiles ----
        #pragma unroll
        for (int ks = 0; ks < 4; ++ks) {
            f16x8 bp0 = *(const f16x8*)&Ps[lm * P_STRIDE + ks * 16 + lh * 8];
            f16x8 bp1 = *(const f16x8*)&Ps[(32 + lm) * P_STRIDE + ks * 16 + lh * 8];
            f16x8 av0 = *(const f16x8*)&Vs[(w * 64 + lm) * V_STRIDE + ks * 16 + lh * 8];
            f16x8 av1 = *(const f16x8*)&Vs[(w * 64 + 32 + lm) * V_STRIDE + ks * 16 + lh * 8];
            facc[0] = __builtin_amdgcn_mfma_f32_32x32x16_f16(av0, bp0, facc[0], 0, 0, 0);
            facc[1] = __builtin_amdgcn_mfma_f32_32x32x16_f16(av0, bp1, facc[1], 0, 0, 0);
            facc[2] = __builtin_amdgcn_mfma_f32_32x32x16_f16(av1, bp0, facc[2], 0, 0, 0);
            facc[3] = __builtin_amdgcn_mfma_f32_32x32x16_f16(av1, bp1, facc[3], 0, 0, 0);
        }
        // no trailing barrier: next iteration only writes Ks (unread since
        // this chunk's S-phase, all waves past barrier C).
    }

    // ---- fused LayerNorm over c per position p ----
    float ps0 = 0.f, ps1 = 0.f, pq0 = 0.f, pq1 = 0.f;
    #pragma unroll
    for (int ii = 0; ii < 2; ++ii) {
        #pragma unroll
        for (int r = 0; r < 16; ++r) {
            float a = facc[ii * 2 + 0][r];
            float c = facc[ii * 2 + 1][r];
            ps0 += a; pq0 += a * a;
            ps1 += c; pq1 += c * c;
        }
    }
    ps0 += __shfl_xor(ps0, 32); pq0 += __shfl_xor(pq0, 32);
    ps1 += __shfl_xor(ps1, 32); pq1 += __shfl_xor(pq1, 32);
    if (lh == 0) {
        redS[w * 64 + lm] = ps0;        redQ[w * 64 + lm] = pq0;
        redS[w * 64 + 32 + lm] = ps1;   redQ[w * 64 + 32 + lm] = pq1;
    }
    __syncthreads();
    if (t < 64) {
        float s = redS[t] + redS[64 + t] + redS[128 + t] + redS[192 + t];
        float q = redQ[t] + redQ[64 + t] + redQ[128 + t] + redQ[192 + t];
        float mean = s * (1.0f / 256.0f);
        float var  = q * (1.0f / 256.0f) - mean * mean;
        mu_s[t] = mean;
        rs_s[t] = rsqrtf(var + EPSV);
    }
    __syncthreads();
    #pragma unroll
    for (int ii = 0; ii < 2; ++ii) {
        #pragma unroll
        for (int jj = 0; jj < 2; ++jj) {
            int p = jj * 32 + lm;
            float mu = mu_s[p], rs = rs_s[p];
            float* dst = out + (size_t)b * CDIM * NPOS + p0 + p;
            #pragma unroll
            for (int r = 0; r < 16; ++r) {
                int c = w * 64 + ii * 32 + (r & 3) + 8 * (r >> 2) + 4 * lh;
                float vL = facc[ii * 2 + jj][r];
                dst[(size_t)c * NPOS] = (vL - mu) * rs * lnw_s[c] + lnb_s[c];
            }
        }
    }
}

// ---------------------------------------------------------------------------
extern "C" void kernel_launch(void* const* d_in, const int* in_sizes, int n_in,
                              void* d_out, int out_size, void* d_ws, size_t ws_size,
                              hipStream_t stream)
{
    const float* x1  = (const float*)d_in[0];
    const float* x2  = (const float*)d_in[1];
    const float* qw  = (const float*)d_in[2];
    const float* qb  = (const float*)d_in[3];
    const float* kw  = (const float*)d_in[4];
    const float* kb  = (const float*)d_in[5];
    const float* vw  = (const float*)d_in[6];
    const float* vb  = (const float*)d_in[7];
    const float* lnw = (const float*)d_in[8];
    const float* lnb = (const float*)d_in[9];

    // Workspace: Q,K f16 [B][N][C]; V f16 [B][C][N]  (3 x 8 MB = 24 MB)
    f16* Qg = (f16*)d_ws;
    f16* Kg = Qg + (size_t)BATCH * NPOS * CDIM;
    f16* Vg = Kg + (size_t)BATCH * NPOS * CDIM;

    qkv_kernel<<<256, 256, 0, stream>>>(x1, x2, qw, qb, kw, kb, vw, vb, Qg, Kg, Vg);
    attn_kernel<<<256, 256, 0, stream>>>(Qg, Kg, Vg, lnw, lnb, (float*)d_out);
}

// Round 3
// 242.868 us; speedup vs baseline: 1.1991x; 1.0867x over previous
//
#include <hip/hip_runtime.h>

// B=4, C=256, H=W=64 (N=4096). QKV 1x1conv -> spatial attention (softmax over
// j only => independent per-64-key-chunk softmax) -> channel LayerNorm.
// f16 MFMA 32x32x16, fp32 accumulation.
//
// R3: qkv split into prep (x-transpose + weight f16 convert; high occupancy,
// coalesced) + gemm (768 blocks, 2/CU, weights from L2, LDS-assisted coalesced
// stores). attn: Q fragments hoisted to registers, Qs LDS removed.

#define CDIM 256
#define NPOS 4096
#define BATCH 4
#define EPSV 1e-5f

typedef _Float16 f16;
typedef __attribute__((ext_vector_type(8))) _Float16 f16x8;
typedef __attribute__((ext_vector_type(4))) float f32x4;
typedef __attribute__((ext_vector_type(16))) float f32x16;

#define QK_STRIDE 264   // f16 elems; 528B = 33*16 -> b128-aligned rows
#define V_STRIDE  72    // 144B = 9*16
#define S_STRIDE  68    // f32; 272B = 17*16
#define P_STRIDE  72
#define DS_V_STRIDE 72

// MFMA 32x32x16 f16:
//   A: lane l holds A[m=l&31][k=(l>>5)*8+j]
//   B: lane l holds B[k=(l>>5)*8+j][n=l&31]
//   C/D: lane l, reg r -> col=l&31, row=(r&3)+8*(r>>2)+4*(l>>5)

static __device__ __forceinline__ f16x8 cvt8(const float* __restrict__ p) {
    float4 w0 = *(const float4*)p;
    float4 w1 = *(const float4*)(p + 4);
    f16x8 r;
    r[0] = (f16)w0.x; r[1] = (f16)w0.y; r[2] = (f16)w0.z; r[3] = (f16)w0.w;
    r[4] = (f16)w1.x; r[5] = (f16)w1.y; r[6] = (f16)w1.z; r[7] = (f16)w1.w;
    return r;
}

// ---------------------------------------------------------------------------
// prep: blocks 0..2047 transpose x1/x2 [C][N] fp32 -> [N][C] f16 (64x64 tiles);
// blocks 2048..2059 convert weights fp32 -> f16 [o][c].
// ---------------------------------------------------------------------------
__global__ __launch_bounds__(256, 4) void prep_kernel(
    const float* __restrict__ x1, const float* __restrict__ x2,
    const float* __restrict__ qw, const float* __restrict__ kw,
    const float* __restrict__ vw,
    f16* __restrict__ X1T, f16* __restrict__ X2T, f16* __restrict__ W16)
{
    const int id = blockIdx.x;
    const int t  = threadIdx.x;
    if (id < 2048) {
        __shared__ f16 T[64 * 72];   // [n_local][c_local], 9216 B
        const float* xs = (id & 1) ? x2 : x1;
        f16* dst        = (id & 1) ? X2T : X1T;
        const int t2 = id >> 1;
        const int b  = t2 >> 8;
        const int rm = t2 & 255;
        const int c0 = (rm >> 6) * 64;
        const int n0 = (rm & 63) * 64;
        const float* src = xs + ((size_t)b * CDIM + c0) * NPOS + n0;
        const int rr = t >> 6, col = t & 63;
        #pragma unroll
        for (int j = 0; j < 16; ++j) {
            int row = rr + j * 4;                        // c_local
            T[col * 72 + row] = (f16)src[(size_t)row * NPOS + col];
        }
        __syncthreads();
        const int n = t >> 3, lc = (t & 7) * 8;
        f16* d0 = dst + ((size_t)b * NPOS + n0) * CDIM + c0;
        #pragma unroll
        for (int j = 0; j < 2; ++j) {
            int nn = n + j * 32;
            *(f16x8*)(d0 + (size_t)nn * CDIM + lc) = *(const f16x8*)&T[nn * 72 + lc];
        }
    } else {
        const int wblk = id - 2048;          // 0..11
        const int pr = wblk >> 2, h = wblk & 3;
        const float* W = (pr == 0 ? qw : pr == 1 ? kw : vw) + (size_t)h * 64 * CDIM;
        f16* D = W16 + (size_t)pr * CDIM * CDIM + (size_t)h * 64 * CDIM;
        #pragma unroll
        for (int i = 0; i < 8; ++i) {
            int g = t + i * 256;
            int row = g >> 5, col = (g & 31) * 8;
            *(f16x8*)(D + (size_t)row * CDIM + col) = cvt8(W + (size_t)row * CDIM + col);
        }
    }
}

// ---------------------------------------------------------------------------
// gemm: grid 768 = proj(3) x b(4) x ptile(64). Per block: 64 positions x 256
// outputs. x tile staged f16x8-coalesced to LDS; weight fragments read
// directly from L2 (128 KB/block, shared across blocks). Epilogue assembles
// output tiles in LDS, then fully-coalesced global stores.
// Q,K -> [B][N][C] f16; V -> [B][C][N] f16.
// ---------------------------------------------------------------------------
__global__ __launch_bounds__(256, 2) void gemm_kernel(
    const f16* __restrict__ X1T, const f16* __restrict__ X2T,
    const f16* __restrict__ W16,
    const float* __restrict__ qb, const float* __restrict__ kb,
    const float* __restrict__ vb,
    f16* __restrict__ Qg, f16* __restrict__ Kg, f16* __restrict__ Vg)
{
    __shared__ f16 Xs[64 * QK_STRIDE];   // 33792 B  [p][c]
    __shared__ f16 Ds[256 * 72];         // 36864 B  union: QK [p][o]@264 / V [o][p]@72
    __shared__ float biasS[256];

    const int id = blockIdx.x;
    const int pr  = id >> 8;             // 0=Q 1=K 2=V
    const int rem = id & 255;
    const int b   = rem >> 6;
    const int p0  = (rem & 63) << 6;
    const f16* XT = (pr == 0) ? X1T : X2T;
    const f16* Wp = W16 + (size_t)pr * CDIM * CDIM;
    const float* bias = pr == 0 ? qb : pr == 1 ? kb : vb;

    const int t = threadIdx.x, w = t >> 6, l = t & 63, lm = l & 31, lh = l >> 5;

    biasS[t] = bias[t];
    // stage x tile [64][256] f16, 1KB per wave-instr
    #pragma unroll
    for (int it = 0; it < 8; ++it) {
        int p = w * 16 + it * 2 + lh;
        *(f16x8*)&Xs[p * QK_STRIDE + lm * 8] =
            *(const f16x8*)(XT + ((size_t)(b * NPOS + p0 + p)) * CDIM + lm * 8);
    }
    __syncthreads();

    // wave w covers o-strip [w*64, w*64+64)
    f32x16 acc[2][2] = {};   // QK: [pt][oi]; V: [oi][pt]
    for (int ks = 0; ks < 16; ++ks) {
        f16x8 x0 = *(const f16x8*)&Xs[lm * QK_STRIDE + ks * 16 + lh * 8];
        f16x8 x1v = *(const f16x8*)&Xs[(32 + lm) * QK_STRIDE + ks * 16 + lh * 8];
        f16x8 w0 = *(const f16x8*)(Wp + (size_t)(w * 64 + lm) * CDIM + ks * 16 + lh * 8);
        f16x8 w1 = *(const f16x8*)(Wp + (size_t)(w * 64 + 32 + lm) * CDIM + ks * 16 + lh * 8);
        if (pr < 2) {
            acc[0][0] = __builtin_amdgcn_mfma_f32_32x32x16_f16(x0, w0, acc[0][0], 0, 0, 0);
            acc[0][1] = __builtin_amdgcn_mfma_f32_32x32x16_f16(x0, w1, acc[0][1], 0, 0, 0);
            acc[1][0] = __builtin_amdgcn_mfma_f32_32x32x16_f16(x1v, w0, acc[1][0], 0, 0, 0);
            acc[1][1] = __builtin_amdgcn_mfma_f32_32x32x16_f16(x1v, w1, acc[1][1], 0, 0, 0);
        } else {
            acc[0][0] = __builtin_amdgcn_mfma_f32_32x32x16_f16(w0, x0, acc[0][0], 0, 0, 0);
            acc[0][1] = __builtin_amdgcn_mfma_f32_32x32x16_f16(w0, x1v, acc[0][1], 0, 0, 0);
            acc[1][0] = __builtin_amdgcn_mfma_f32_32x32x16_f16(w1, x0, acc[1][0], 0, 0, 0);
            acc[1][1] = __builtin_amdgcn_mfma_f32_32x32x16_f16(w1, x1v, acc[1][1], 0, 0, 0);
        }
    }

    if (pr < 2) {
        // D[p][o]: stage to Ds[p][o]@264, then coalesced row stores
        #pragma unroll
        for (int pt = 0; pt < 2; ++pt)
            #pragma unroll
            for (int oi = 0; oi < 2; ++oi) {
                int oc = w * 64 + oi * 32 + lm;
                float bv = biasS[oc];
                #pragma unroll
                for (int r = 0; r < 16; ++r) {
                    int p = pt * 32 + (r & 3) + 8 * (r >> 2) + 4 * lh;
                    Ds[p * QK_STRIDE + oc] = (f16)(acc[pt][oi][r] + bv);
                }
            }
        __syncthreads();
        f16* Out = (pr == 0) ? Qg : Kg;
        #pragma unroll
        for (int it = 0; it < 8; ++it) {
            int p = w * 16 + it * 2 + lh;
            *(f16x8*)(Out + ((size_t)(b * NPOS + p0 + p)) * CDIM + lm * 8) =
                *(const f16x8*)&Ds[p * QK_STRIDE + lm * 8];
        }
    } else {
        // D[o][p]: stage to Ds[o][p]@72 (wave-private strip), coalesced stores
        #pragma unroll
        for (int oi = 0; oi < 2; ++oi)
            #pragma unroll
            for (int pt = 0; pt < 2; ++pt) {
                #pragma unroll
                for (int r = 0; r < 16; ++r) {
                    int ol = oi * 32 + (r & 3) + 8 * (r >> 2) + 4 * lh;
                    Ds[(w * 64 + ol) * DS_V_STRIDE + pt * 32 + lm] =
                        (f16)(acc[oi][pt][r] + biasS[w * 64 + ol]);
                }
            }
        __syncthreads();
        #pragma unroll
        for (int it = 0; it < 8; ++it) {
            int ol = it * 8 + (l >> 3);
            int cl = (l & 7) * 8;
            *(f16x8*)(Vg + ((size_t)(b * CDIM + w * 64 + ol)) * NPOS + p0 + cl) =
                *(const f16x8*)&Ds[(w * 64 + ol) * DS_V_STRIDE + cl];
        }
    }
}

// ---------------------------------------------------------------------------
// attn: grid 256 = (b<<6 | qtile), 256 thr. Q fragments in registers (no Qs);
// K/V prefetched one chunk ahead; 3 barriers/chunk; fused LayerNorm.
// ---------------------------------------------------------------------------
__global__ __launch_bounds__(256, 1) void attn_kernel(
    const f16* __restrict__ Qg, const f16* __restrict__ Kg, const f16* __restrict__ Vg,
    const float* __restrict__ ln_w, const float* __restrict__ ln_b,
    float* __restrict__ out)
{
    __shared__ f16   Ks[64 * QK_STRIDE];    // 33792 B  [key][c]
    __shared__ f16   Vs[256 * V_STRIDE];    // 36864 B  [c][key]
    __shared__ float Ss[64 * S_STRIDE];     // 17408 B  [p][key]
    __shared__ f16   Ps[64 * P_STRIDE];     //  9216 B  [p][key]
    __shared__ float lnw_s[256], lnb_s[256];
    __shared__ float redS[4 * 64], redQ[4 * 64], mu_s[64], rs_s[64];

    const int t  = threadIdx.x;
    const int b  = blockIdx.x >> 6;
    const int p0 = (blockIdx.x & 63) << 6;
    const int w  = t >> 6;
    const int l  = t & 63;
    const int lm = l & 31;
    const int lh = l >> 5;

    lnw_s[t] = ln_w[t];
    lnb_s[t] = ln_b[t];

    const int spt = w & 1;    // wave's S tile: p-tile spt, key-tile skt
    const int skt = w >> 1;

    // Q fragments for this wave's p-tile, straight from global (L2-warm).
    f16x8 qf[16];
    {
        const f16* qptr = Qg + (size_t)(b * NPOS + p0 + spt * 32 + lm) * CDIM + lh * 8;
        #pragma unroll
        for (int ks = 0; ks < 16; ++ks) qf[ks] = *(const f16x8*)(qptr + ks * 16);
    }

    // K/V prefetch registers (one chunk ahead).
    const int kr = t >> 5, koff = (t & 31) * 8;
    const int vr = t >> 3, voff = (t & 7) * 8;
    f16x8 kreg[8], vreg[8];
    auto issue_loads = [&](int ch) {
        const int i0 = ch * 64;
        #pragma unroll
        for (int r = 0; r < 8; ++r)
            kreg[r] = *(const f16x8*)(Kg + (size_t)(b * NPOS + i0 + r * 8 + kr) * CDIM + koff);
        #pragma unroll
        for (int r = 0; r < 8; ++r)
            vreg[r] = *(const f16x8*)(Vg + (size_t)(b * CDIM + r * 32 + vr) * NPOS + i0 + voff);
    };
    issue_loads(0);

    f32x16 facc[4] = {};      // persistent F acc: [i=c-tile(2)][j=p-tile(2)]

    for (int ch = 0; ch < 64; ++ch) {
        #pragma unroll
        for (int r = 0; r < 8; ++r)
            *(f16x8*)&Ks[(r * 8 + kr) * QK_STRIDE + koff] = kreg[r];
        __syncthreads();   // A: Ks ready; prev PV done (Vs/Ps free)

        #pragma unroll
        for (int r = 0; r < 8; ++r)
            *(f16x8*)&Vs[(r * 32 + vr) * V_STRIDE + voff] = vreg[r];

        // S = Q K^T
        f32x16 sacc = {};
        for (int ks = 0; ks < 16; ++ks) {
            f16x8 bb = *(const f16x8*)&Ks[(skt * 32 + lm) * QK_STRIDE + ks * 16 + lh * 8];
            sacc = __builtin_amdgcn_mfma_f32_32x32x16_f16(qf[ks], bb, sacc, 0, 0, 0);
        }
        #pragma unroll
        for (int r = 0; r < 16; ++r) {
            int row = (r & 3) + 8 * (r >> 2) + 4 * lh;
            Ss[(spt * 32 + row) * S_STRIDE + skt * 32 + lm] = sacc[r];
        }
        __syncthreads();   // B: Ss ready; Vs writes fenced

        // softmax per row: 4 threads/row x 16 elems
        {
            const int r  = t >> 2;
            const int sg = (t & 3) * 16;
            const float* srow = &Ss[r * S_STRIDE + sg];
            float v[16];
            f32x4 a0 = *(const f32x4*)(srow);
            f32x4 a1 = *(const f32x4*)(srow + 4);
            f32x4 a2 = *(const f32x4*)(srow + 8);
            f32x4 a3 = *(const f32x4*)(srow + 12);
            v[0]=a0[0]; v[1]=a0[1]; v[2]=a0[2]; v[3]=a0[3];
            v[4]=a1[0]; v[5]=a1[1]; v[6]=a1[2]; v[7]=a1[3];
            v[8]=a2[0]; v[9]=a2[1]; v[10]=a2[2]; v[11]=a2[3];
            v[12]=a3[0]; v[13]=a3[1]; v[14]=a3[2]; v[15]=a3[3];
            float m = v[0];
            #pragma unroll
            for (int i = 1; i < 16; ++i) m = fmaxf(m, v[i]);
            m = fmaxf(m, __shfl_xor(m, 1));
            m = fmaxf(m, __shfl_xor(m, 2));
            float s = 0.f;
            #pragma unroll
            for (int i = 0; i < 16; ++i) { float e = __expf(v[i] - m); v[i] = e; s += e; }
            s += __shfl_xor(s, 1);
            s += __shfl_xor(s, 2);
            float inv = __builtin_amdgcn_rcpf(s);
            f16x8 h0, h1;
            #pragma unroll
            for (int i = 0; i < 8; ++i) { h0[i] = (f16)(v[i] * inv); h1[i] = (f16)(v[i + 8] * inv); }
            *(f16x8*)&Ps[r * P_STRIDE + sg]     = h0;
            *(f16x8*)&Ps[r * P_STRIDE + sg + 8] = h1;
        }
        __syncthreads();   // C: Ps ready

        if (ch < 63) issue_loads(ch + 1);   // hidden behind PV

        // F += V * P^T
        #pragma unroll
        for (int ks = 0; ks < 4; ++ks) {
            f16x8 bp0 = *(const f16x8*)&Ps[lm * P_STRIDE + ks * 16 + lh * 8];
            f16x8 bp1 = *(const f16x8*)&Ps[(32 + lm) * P_STRIDE + ks * 16 + lh * 8];
            f16x8 av0 = *(const f16x8*)&Vs[(w * 64 + lm) * V_STRIDE + ks * 16 + lh * 8];
            f16x8 av1 = *(const f16x8*)&Vs[(w * 64 + 32 + lm) * V_STRIDE + ks * 16 + lh * 8];
            facc[0] = __builtin_amdgcn_mfma_f32_32x32x16_f16(av0, bp0, facc[0], 0, 0, 0);
            facc[1] = __builtin_amdgcn_mfma_f32_32x32x16_f16(av0, bp1, facc[1], 0, 0, 0);
            facc[2] = __builtin_amdgcn_mfma_f32_32x32x16_f16(av1, bp0, facc[2], 0, 0, 0);
            facc[3] = __builtin_amdgcn_mfma_f32_32x32x16_f16(av1, bp1, facc[3], 0, 0, 0);
        }
    }

    // fused LayerNorm over c per position p
    float ps0 = 0.f, ps1 = 0.f, pq0 = 0.f, pq1 = 0.f;
    #pragma unroll
    for (int ii = 0; ii < 2; ++ii) {
        #pragma unroll
        for (int r = 0; r < 16; ++r) {
            float a = facc[ii * 2 + 0][r];
            float c = facc[ii * 2 + 1][r];
            ps0 += a; pq0 += a * a;
            ps1 += c; pq1 += c * c;
        }
    }
    ps0 += __shfl_xor(ps0, 32); pq0 += __shfl_xor(pq0, 32);
    ps1 += __shfl_xor(ps1, 32); pq1 += __shfl_xor(pq1, 32);
    if (lh == 0) {
        redS[w * 64 + lm] = ps0;        redQ[w * 64 + lm] = pq0;
        redS[w * 64 + 32 + lm] = ps1;   redQ[w * 64 + 32 + lm] = pq1;
    }
    __syncthreads();
    if (t < 64) {
        float s = redS[t] + redS[64 + t] + redS[128 + t] + redS[192 + t];
        float q = redQ[t] + redQ[64 + t] + redQ[128 + t] + redQ[192 + t];
        float mean = s * (1.0f / 256.0f);
        float var  = q * (1.0f / 256.0f) - mean * mean;
        mu_s[t] = mean;
        rs_s[t] = rsqrtf(var + EPSV);
    }
    __syncthreads();
    #pragma unroll
    for (int ii = 0; ii < 2; ++ii) {
        #pragma unroll
        for (int jj = 0; jj < 2; ++jj) {
            int p = jj * 32 + lm;
            float mu = mu_s[p], rs = rs_s[p];
            float* dst = out + (size_t)b * CDIM * NPOS + p0 + p;
            #pragma unroll
            for (int r = 0; r < 16; ++r) {
                int c = w * 64 + ii * 32 + (r & 3) + 8 * (r >> 2) + 4 * lh;
                float vL = facc[ii * 2 + jj][r];
                dst[(size_t)c * NPOS] = (vL - mu) * rs * lnw_s[c] + lnb_s[c];
            }
        }
    }
}

// ---------------------------------------------------------------------------
extern "C" void kernel_launch(void* const* d_in, const int* in_sizes, int n_in,
                              void* d_out, int out_size, void* d_ws, size_t ws_size,
                              hipStream_t stream)
{
    const float* x1  = (const float*)d_in[0];
    const float* x2  = (const float*)d_in[1];
    const float* qw  = (const float*)d_in[2];
    const float* qb  = (const float*)d_in[3];
    const float* kw  = (const float*)d_in[4];
    const float* kb  = (const float*)d_in[5];
    const float* vw  = (const float*)d_in[6];
    const float* vb  = (const float*)d_in[7];
    const float* lnw = (const float*)d_in[8];
    const float* lnb = (const float*)d_in[9];

    // ws: Qg,Kg (f16 [B][N][C]), Vg (f16 [B][C][N]), X1T,X2T (f16 [B][N][C]),
    // W16 (f16 3x[256][256]) -> total ~42.4 MB
    const size_t tsz = (size_t)BATCH * NPOS * CDIM;
    f16* Qg  = (f16*)d_ws;
    f16* Kg  = Qg + tsz;
    f16* Vg  = Kg + tsz;
    f16* X1T = Vg + tsz;
    f16* X2T = X1T + tsz;
    f16* W16 = X2T + tsz;

    prep_kernel<<<2060, 256, 0, stream>>>(x1, x2, qw, kw, vw, X1T, X2T, W16);
    gemm_kernel<<<768, 256, 0, stream>>>(X1T, X2T, W16, qb, kb, vb, Qg, Kg, Vg);
    attn_kernel<<<256, 256, 0, stream>>>(Qg, Kg, Vg, lnw, lnb, (float*)d_out);
}